// Round 1
// baseline (91.372 us; speedup 1.0000x reference)
//
#include <hip/hip_runtime.h>
#include <hip/hip_bf16.h>
#include <stdint.h>

// Problem constants (ni = nt = 1024, d = 64, 2d = 128, TAU = 0.5)
#define NI   1024
#define NT   1024
#define DD   64
#define K2   128   // 2*d

// ---------------------------------------------------------------------------
// Kernel 1: precompute.
//  - STE: s = sign(x)/8
//  - pack per-row sign bits / nonzero bits (for posE popcount dot)
//  - h rows: a_ik = b1[k] + sum_c img_s[i,c]*W1[k,c]     (images, b1 folded)
//            b_jk =          sum_c txt_s[j,c]*W1[k,64+c] (texts)
//    stored TRANSPOSED: At[k][i], Bt[k][j]  (for coalesced/scalar access)
//  - rank-1 terms: rA_i = sum_k W2[k]*a_ik ; rB_j = sum_k W2[k]*b_jk
// One block = 8 rows, 128 threads (thread t = output index k).
// ---------------------------------------------------------------------------
__global__ __launch_bounds__(128) void precompute_kernel(
    const float* __restrict__ img, const float* __restrict__ txt,
    const float* __restrict__ W1,  const float* __restrict__ b1,
    const float* __restrict__ W2,
    float* __restrict__ At, float* __restrict__ Bt,
    float* __restrict__ rA, float* __restrict__ rB,
    unsigned long long* __restrict__ img_x, unsigned long long* __restrict__ img_m,
    unsigned long long* __restrict__ txt_x, unsigned long long* __restrict__ txt_m)
{
    const int tid = threadIdx.x;
    const int rb  = blockIdx.x * 8;            // row base in combined [0, 2048)
    const bool is_img = (rb < NI);
    const int lrb = is_img ? rb : rb - NI;     // local row base
    const float* src = (is_img ? img : txt) + lrb * DD;

    __shared__ float sv[8 * 64];               // STE'd rows

    // load + STE (block of 8 rows is contiguous in global: 512 floats)
    for (int idx = tid; idx < 8 * 64; idx += 128) {
        float x = src[idx];
        sv[idx] = (x > 0.f) ? 0.125f : ((x < 0.f) ? -0.125f : 0.f);
    }
    __syncthreads();

    // sign / nonzero bit packing: wave 0 only (64 lanes = 64 columns)
    if (tid < 64) {
        #pragma unroll
        for (int r = 0; r < 8; ++r) {
            float s = sv[r * 64 + tid];
            unsigned long long xb = __ballot(s < 0.f);
            unsigned long long mb = __ballot(s != 0.f);
            if (tid == 0) {
                if (is_img) { img_x[lrb + r] = xb; img_m[lrb + r] = mb; }
                else        { txt_x[lrb + r] = xb; txt_m[lrb + r] = mb; }
            }
        }
    }

    // h compute: thread t owns output index k = t
    const int t = tid;
    const int off = is_img ? 0 : DD;
    const float* wrow = W1 + t * K2 + off;
    float h[8];
    const float hinit = is_img ? b1[t] : 0.f;   // fold b1 into image side
    #pragma unroll
    for (int r = 0; r < 8; ++r) h[r] = hinit;

    for (int c = 0; c < DD; ++c) {
        float w = wrow[c];
        #pragma unroll
        for (int r = 0; r < 8; ++r) h[r] = fmaf(w, sv[r * 64 + c], h[r]);
    }

    // transposed store
    float* T = is_img ? At : Bt;
    #pragma unroll
    for (int r = 0; r < 8; ++r) T[t * 1024 + lrb + r] = h[r];

    // rank-1 reduction: sum over k (=threads) of W2[k]*h
    __shared__ float red[128 * 8];
    const float w2t = W2[t];
    #pragma unroll
    for (int r = 0; r < 8; ++r) red[t * 8 + r] = w2t * h[r];
    __syncthreads();
    if (t < 8) {
        float s = 0.f;
        for (int u = 0; u < 128; ++u) s += red[u * 8 + t];
        if (is_img) rA[lrb + t] = s; else rB[lrb + t] = s;
    }
}

// ---------------------------------------------------------------------------
// Kernel 2: pairwise energy.
//  negE[i,j] = 0.5*(rA_i + rB_j + sum_k W2[k]*|a_ik + b_jk|) + b2
//  posE[i,j] via popcount on packed sign bits.
//  out[p] = { exp(clip(pos*2,±15)), exp(clip(neg*2,±15)) }, p = i*NT + j.
// Block: 256 threads, J-tile = 256 (lane = j -> coalesced loads/stores),
//        I-tile = 8 (register-blocked; a-values wave-uniform -> scalar loads).
// Grid: 128 i-tiles x 4 j-tiles = 512 blocks.
// ---------------------------------------------------------------------------
__global__ __launch_bounds__(256) void pair_kernel(
    const float* __restrict__ At, const float* __restrict__ Bt,
    const float* __restrict__ rA, const float* __restrict__ rB,
    const float* __restrict__ W2, const float* __restrict__ b2,
    const unsigned long long* __restrict__ img_x, const unsigned long long* __restrict__ img_m,
    const unsigned long long* __restrict__ txt_x, const unsigned long long* __restrict__ txt_m,
    const int* __restrict__ taskp,
    float2* __restrict__ out)
{
    const int tid = threadIdx.x;
    const int bid = blockIdx.x;
    const int I0  = (bid >> 2) * 8;
    const int j   = (bid & 3) * 256 + tid;

    float acc[8];
    #pragma unroll
    for (int ii = 0; ii < 8; ++ii) acc[ii] = 0.f;

    #pragma unroll 4
    for (int k = 0; k < K2; ++k) {
        const float b = Bt[k * 1024 + j];        // coalesced vector load
        const float w = W2[k];                   // uniform -> SGPR
        const float* ak = At + k * 1024 + I0;    // uniform -> s_load_dwordx8
        #pragma unroll
        for (int ii = 0; ii < 8; ++ii) {
            float t = ak[ii] + b;                          // v_add (sgpr + vgpr)
            acc[ii] = fmaf(w, __builtin_fabsf(t), acc[ii]); // v_fma with |.| modifier
        }
    }

    const int task = *taskp;
    // scalar side (index i): img if task else txt; vector side (index j): the other
    const unsigned long long* xi_a = task ? img_x : txt_x;
    const unsigned long long* mi_a = task ? img_m : txt_m;
    const unsigned long long* xj_a = task ? txt_x : img_x;
    const unsigned long long* mj_a = task ? txt_m : img_m;

    const unsigned long long xj = xj_a[j];
    const unsigned long long mj = mj_a[j];
    const float rBj = rB[j];
    const float b2v = b2[0];

    #pragma unroll
    for (int ii = 0; ii < 8; ++ii) {
        const int i = I0 + ii;
        const unsigned long long xi = xi_a[i];
        const unsigned long long mi = mi_a[i];
        const unsigned long long valid = mi & mj;
        const int nv = __popcll(valid);
        const int df = __popcll((xi ^ xj) & valid);
        const float pos = (float)(nv - 2 * df) * (1.0f / 64.0f);
        const float neg = 0.5f * (rA[i] + rBj + acc[ii]) + b2v;

        const float pe = __expf(fminf(fmaxf(pos * 2.0f, -15.0f), 15.0f));
        const float ne = __expf(fminf(fmaxf(neg * 2.0f, -15.0f), 15.0f));
        out[i * NT + j] = make_float2(pe, ne);   // coalesced 8B/lane store
    }
}

// ---------------------------------------------------------------------------
extern "C" void kernel_launch(void* const* d_in, const int* in_sizes, int n_in,
                              void* d_out, int out_size, void* d_ws, size_t ws_size,
                              hipStream_t stream) {
    const float* img = (const float*)d_in[0];
    const float* txt = (const float*)d_in[1];
    const float* W1  = (const float*)d_in[2];
    const float* b1  = (const float*)d_in[3];
    const float* W2  = (const float*)d_in[4];
    const float* b2  = (const float*)d_in[5];
    const int*  task = (const int*)d_in[6];

    // workspace layout (floats then u64s) — ~1.1 MB total
    float* At = (float*)d_ws;                 // [128][1024]
    float* Bt = At + K2 * 1024;               // [128][1024]
    float* rA = Bt + K2 * 1024;               // [1024]
    float* rB = rA + 1024;                    // [1024]
    unsigned long long* img_x = (unsigned long long*)(rB + 1024);
    unsigned long long* img_m = img_x + 1024;
    unsigned long long* txt_x = img_m + 1024;
    unsigned long long* txt_m = txt_x + 1024;

    hipLaunchKernelGGL(precompute_kernel, dim3(256), dim3(128), 0, stream,
                       img, txt, W1, b1, W2, At, Bt, rA, rB,
                       img_x, img_m, txt_x, txt_m);

    hipLaunchKernelGGL(pair_kernel, dim3(512), dim3(256), 0, stream,
                       At, Bt, rA, rB, W2, b2,
                       img_x, img_m, txt_x, txt_m, task,
                       (float2*)d_out);
}